// Round 1
// baseline (1112.988 us; speedup 1.0000x reference)
//
#include <hip/hip_runtime.h>
#include <math.h>

#define B  8
#define T  200
#define U  100
#define U1 101
#define V  1024
#define NROWS (B * T * U1)   // 161600

// ---------------------------------------------------------------------------
// Kernel 1: per (b,t,u) row of V=1024 logits, compute logsumexp and emit only
// the two needed log-probs:
//   blank_lp[b,t,u] = logits[b,t,u,V-1]          - lse
//   emit_lp [b,t,u] = logits[b,t,u,targets[b,u]] - lse   (u < U)
// One wave (64 lanes) per row; 16 floats/lane via 4x float4 coalesced loads.
// ---------------------------------------------------------------------------
__global__ __launch_bounds__(256) void rnnt_row_lse(
    const float* __restrict__ logits,
    const int*   __restrict__ targets,
    float*       __restrict__ blank_lp,
    float*       __restrict__ emit_lp)
{
    const int wave = threadIdx.x >> 6;
    const int lane = threadIdx.x & 63;
    const int row  = blockIdx.x * 4 + wave;
    if (row >= NROWS) return;

    const float* rp = logits + (long long)row * V;
    const float4* rp4 = (const float4*)rp;

    // 16 elements per lane, coalesced: chunk k covers elements [k*256, k*256+255]
    float4 v0 = rp4[lane];
    float4 v1 = rp4[lane + 64];
    float4 v2 = rp4[lane + 128];
    float4 v3 = rp4[lane + 192];

    float m = fmaxf(fmaxf(fmaxf(v0.x, v0.y), fmaxf(v0.z, v0.w)),
                    fmaxf(fmaxf(v1.x, v1.y), fmaxf(v1.z, v1.w)));
    m = fmaxf(m, fmaxf(fmaxf(fmaxf(v2.x, v2.y), fmaxf(v2.z, v2.w)),
                       fmaxf(fmaxf(v3.x, v3.y), fmaxf(v3.z, v3.w))));
    #pragma unroll
    for (int mask = 32; mask >= 1; mask >>= 1)
        m = fmaxf(m, __shfl_xor(m, mask, 64));

    float s = expf(v0.x - m) + expf(v0.y - m) + expf(v0.z - m) + expf(v0.w - m)
            + expf(v1.x - m) + expf(v1.y - m) + expf(v1.z - m) + expf(v1.w - m)
            + expf(v2.x - m) + expf(v2.y - m) + expf(v2.z - m) + expf(v2.w - m)
            + expf(v3.x - m) + expf(v3.y - m) + expf(v3.z - m) + expf(v3.w - m);
    #pragma unroll
    for (int mask = 32; mask >= 1; mask >>= 1)
        s += __shfl_xor(s, mask, 64);

    const float lse = m + logf(s);

    if (lane == 0) {
        const int b   = row / (T * U1);
        const int rem = row - b * (T * U1);
        const int t   = rem / U1;
        const int u   = rem - t * U1;
        // scalar re-reads hit L1 (row just loaded)
        blank_lp[row] = rp[V - 1] - lse;
        if (u < U) {
            const int tgt = targets[b * U + u];
            emit_lp[(b * T + t) * U + u] = rp[tgt] - lse;
        }
    }
}

// ---------------------------------------------------------------------------
// Kernel 2: alpha forward recursion, one block per batch element.
// Anti-diagonal wavefront: diag d holds cells (t,u) with t+u=d; both parents
// (t-1,u) and (t,u-1) live on diag d-1, kept in LDS. The blank/emit log-probs
// for diag d+1 are prefetched into registers BEFORE the barrier so their L2
// latency hides behind __syncthreads().
//   alpha[0][0]=0
//   alpha[t][u]=logaddexp(alpha[t-1][u]+blank[t-1][u], alpha[t][u-1]+emit[t][u-1])
//   cost = -(alpha[t_last][tl] + blank[t_last][tl])
// ---------------------------------------------------------------------------
__global__ __launch_bounds__(128) void rnnt_alpha(
    const float* __restrict__ blank_lp,
    const float* __restrict__ emit_lp,
    const int*   __restrict__ logit_lengths,
    const int*   __restrict__ target_lengths,
    float*       __restrict__ out)
{
    const int b      = blockIdx.x;
    const int u      = threadIdx.x;          // thread u owns column u forever
    const int t_last = logit_lengths[b] - 1;
    const int tl     = target_lengths[b];

    const float* blp = blank_lp + b * (T * U1);
    const float* elp = emit_lp  + b * (T * U);

    __shared__ float diag[2][U1];

    float bl_v = 0.f, em_v = 0.f;            // prefetched lp's for this cell
    int cur = 0;

    for (int d = 0; d <= (T - 1) + (U1 - 1); ++d) {
        const int t = d - u;
        const bool active = (u < U1) && (t >= 0) && (t < T);

        if (active) {
            float a;
            if (d == 0) {
                a = 0.f;
            } else {
                const float top  = (t > 0) ? diag[cur ^ 1][u]     + bl_v : -INFINITY;
                const float left = (u > 0) ? diag[cur ^ 1][u - 1] + em_v : -INFINITY;
                const float mx = fmaxf(top, left);
                const float mn = fminf(top, left);
                a = mx + log1pf(expf(mn - mx));   // mn=-inf -> exp=0 -> a=mx
            }
            diag[cur][u] = a;
            if (t == t_last && u == tl)
                out[b] = -(a + blp[t_last * U1 + tl]);
        }

        // prefetch lp's for diag d+1 (addresses independent of alpha values;
        // vmcnt wait lands at consumption, after the barrier)
        {
            const int tn = d + 1 - u;         // this thread's t on next diag
            if (u < U1 && tn >= 1 && tn < T)  bl_v = blp[(tn - 1) * U1 + u];
            if (u >= 1 && u < U1 && tn >= 0 && tn < T) em_v = elp[tn * U + (u - 1)];
        }

        __syncthreads();
        cur ^= 1;
    }
}

extern "C" void kernel_launch(void* const* d_in, const int* in_sizes, int n_in,
                              void* d_out, int out_size, void* d_ws, size_t ws_size,
                              hipStream_t stream) {
    const float* logits         = (const float*)d_in[0];
    const int*   targets        = (const int*)d_in[1];
    const int*   logit_lengths  = (const int*)d_in[2];
    const int*   target_lengths = (const int*)d_in[3];
    float*       out            = (float*)d_out;

    float* blank_lp = (float*)d_ws;                 // B*T*U1 floats
    float* emit_lp  = blank_lp + (size_t)B * T * U1; // B*T*U floats

    const int rows_per_block = 4;   // 4 waves/block, 1 row/wave
    const int grid1 = (NROWS + rows_per_block - 1) / rows_per_block;
    rnnt_row_lse<<<grid1, 256, 0, stream>>>(logits, targets, blank_lp, emit_lp);

    rnnt_alpha<<<B, 128, 0, stream>>>(blank_lp, emit_lp,
                                      logit_lengths, target_lengths, out);
}